// Round 1
// baseline (467.829 us; speedup 1.0000x reference)
//
#include <hip/hip_runtime.h>
#include <hip/hip_bf16.h>
#include <math.h>

// ---- problem constants ----
#define BB 2
#define HH 50
#define WW 50
#define NN 2500            // H*W
#define PP 4
#define CAP 128            // max neighbors per row (density 1% of 2500 ~ 25, P(>128) ~ 0)
#define LRELU_SLOPE 0.2f
#define ZTOL 1e-9f

static inline int cdiv(int a, int b) { return (a + b - 1) / b; }

// ---------- elementwise ----------
__global__ void k_sigmoid(const float* in, float* out, int n) {
    int i = blockIdx.x * blockDim.x + threadIdx.x;
    if (i < n) out[i] = 1.0f / (1.0f + expf(-in[i]));
}

// ---------- generic 3x3 conv (cross-correlation) + relu, padval-padded ----------
__global__ void k_conv3x3_relu(const float* __restrict__ in, const float* __restrict__ w,
                               const float* __restrict__ bias, float* __restrict__ out,
                               int Cin, int Cout, float padval) {
    int idx = blockIdx.x * blockDim.x + threadIdx.x;
    int total = BB * Cout * HH * WW;
    if (idx >= total) return;
    int x = idx % WW;
    int y = (idx / WW) % HH;
    int oc = (idx / (WW * HH)) % Cout;
    int b = idx / (WW * HH * Cout);
    float acc = bias[oc];
    for (int ic = 0; ic < Cin; ++ic) {
        const float* ip = in + ((size_t)(b * Cin + ic)) * HH * WW;
        const float* wp = w + ((size_t)(oc * Cin + ic)) * 9;
        for (int ky = 0; ky < 3; ++ky) {
            int yy = y + ky - 1;
            for (int kx = 0; kx < 3; ++kx) {
                int xx = x + kx - 1;
                float v = (yy >= 0 && yy < HH && xx >= 0 && xx < WW)
                              ? ip[yy * WW + xx] : padval;
                acc += v * wp[ky * 3 + kx];
            }
        }
    }
    out[idx] = fmaxf(acc, 0.0f);
}

// ---------- build sparse adjacency from Slist (B,2,N,N) ----------
// layout: row index r = (s*BB + b)*NN + i ; cols/vals [r*CAP + k], counts[r]
__global__ void k_build_adj(const float* __restrict__ S, int* __restrict__ counts,
                            int* __restrict__ cols, float* __restrict__ vals) {
    int gid = blockIdx.x * blockDim.x + threadIdx.x;
    int wid = gid >> 6;
    int lane = threadIdx.x & 63;
    int nrows = 2 * BB * NN;
    if (wid >= nrows) return;
    int i = wid % NN;
    int b = (wid / NN) % BB;
    int s = wid / (NN * BB);
    const float* Srow = S + (((size_t)(b * 2 + s)) * NN + i) * NN;
    size_t rowbase = (size_t)wid * CAP;
    int cnt = 0;
    for (int base = 0; base < NN; base += 64) {
        int j = base + lane;
        bool act = (j < NN) && (fabsf(Srow[j]) > ZTOL);
        unsigned long long m = __ballot(act);
        int off = __popcll(m & ((1ull << lane) - 1ull));
        if (act && (cnt + off) < CAP) {
            cols[rowbase + cnt + off] = j;
            vals[rowbase + cnt + off] = Srow[j];
        }
        cnt += __popcll(m);
    }
    if (lane == 0) counts[wid] = (cnt < CAP) ? cnt : CAP;
}

// ---------- transpose (B,G,N) -> (B,N,G) ----------
__global__ void k_transpose(const float* __restrict__ x, float* __restrict__ xT, int G) {
    int idx = blockIdx.x * blockDim.x + threadIdx.x;
    int total = BB * NN * G;
    if (idx >= total) return;
    int g = idx % G;
    int n = (idx / G) % NN;
    int b = idx / (G * NN);
    xT[idx] = x[((size_t)(b * G + g)) * NN + n];
}

// ---------- GAT: s1[b,p,n] = sum_g a[p,g] x[b,g,n]; s2 with a[p,G+g] ----------
__global__ void k_gat_s1s2(const float* __restrict__ xT, const float* __restrict__ a, int G,
                           float* __restrict__ s1, float* __restrict__ s2) {
    int idx = blockIdx.x * blockDim.x + threadIdx.x;
    int total = BB * PP * NN;
    if (idx >= total) return;
    int n = idx % NN;
    int p = (idx / NN) % PP;
    int b = idx / (NN * PP);
    const float* ar = a + p * 2 * G;
    const float* xr = xT + ((size_t)b * NN + n) * G;
    float a1 = 0.f, a2 = 0.f;
    for (int g = 0; g < G; ++g) {
        float v = xr[g];
        a1 += ar[g] * v;
        a2 += ar[G + g] * v;
    }
    s1[idx] = a1;
    s2[idx] = a2;
}

// ---------- GAT main: one 64-thread block per (b,p,i) ----------
// out[b, p*F+f, i] (+)= sum_g xT[b,i,g]*W0[g,f] + z1[g]*W1[g,f] + bias[f]
__global__ void k_gat_main(const float* __restrict__ xT, int G,
                           const float* __restrict__ s1, const float* __restrict__ s2,
                           const int* __restrict__ counts, const int* __restrict__ cols,
                           const float* __restrict__ vals,
                           const float* __restrict__ Wf, const float* __restrict__ bias, int F,
                           float* __restrict__ out, int PF, int accumulate) {
    __shared__ float wsh[CAP];
    __shared__ int csh[CAP];
    __shared__ float z1sh[64];

    int bid = blockIdx.x;                 // (b,p,i)
    int i = bid % NN;
    int p = (bid / NN) % PP;
    int b = bid / (NN * PP);
    int t = threadIdx.x;

    int cnt = counts[b * NN + i];
    size_t rowbase = ((size_t)(b * NN + i)) * CAP;
    float s1i = s1[(b * PP + p) * NN + i];

    // phase 1: leaky-relu scores, masked softmax, * S value
    float lmax = -1e30f;
    for (int jj = t; jj < cnt; jj += 64) {
        int j = cols[rowbase + jj];
        csh[jj] = j;
        float e = s1i + s2[(b * PP + p) * NN + j];
        e = (e < 0.f) ? LRELU_SLOPE * e : e;
        wsh[jj] = e;
        lmax = fmaxf(lmax, e);
    }
    for (int m = 32; m >= 1; m >>= 1) lmax = fmaxf(lmax, __shfl_xor(lmax, m));
    __syncthreads();
    float lsum = 0.f;
    for (int jj = t; jj < cnt; jj += 64) {
        float ex = expf(wsh[jj] - lmax);
        wsh[jj] = ex;
        lsum += ex;
    }
    for (int m = 32; m >= 1; m >>= 1) lsum += __shfl_xor(lsum, m);
    float inv = (cnt > 0) ? 1.0f / lsum : 0.f;
    for (int jj = t; jj < cnt; jj += 64) {
        wsh[jj] = wsh[jj] * inv * vals[rowbase + jj];
    }
    __syncthreads();

    // phase 2: z1[g] = sum_j w[j] * xT[b, col_j, g]   (lane = g, coalesced)
    for (int g = t; g < G; g += 64) {
        float acc = 0.f;
        for (int jj = 0; jj < cnt; ++jj) {
            acc += wsh[jj] * xT[((size_t)b * NN + csh[jj]) * G + g];
        }
        z1sh[g] = acc;
    }
    __syncthreads();

    // phase 3: y[f] = sum_g xT[b,i,g]*W0[g,f] + z1[g]*W1[g,f] + bias[f]
    const float* W0 = Wf + ((size_t)(p * 2 + 0)) * G * F;
    const float* W1 = Wf + ((size_t)(p * 2 + 1)) * G * F;
    const float* xi = xT + ((size_t)b * NN + i) * G;
    for (int f = t; f < F; f += 64) {
        float yv = bias[f];
        for (int g = 0; g < G; ++g) {
            yv += xi[g] * W0[g * F + f] + z1sh[g] * W1[g * F + f];
        }
        int oc = p * F + f;
        float* dst = out + ((size_t)b * PF + oc) * NN + i;
        if (accumulate) *dst += yv; else *dst = yv;
    }
}

// ---------- att = max over spatial (one wave per (b,c)) ----------
__global__ void k_attmax(const float* __restrict__ d, float* __restrict__ att) {
    int wid = blockIdx.x;     // b*128 + c
    int lane = threadIdx.x;
    const float* row = d + (size_t)wid * NN;
    float m = -1e30f;
    for (int n = lane; n < NN; n += 64) m = fmaxf(m, row[n]);
    for (int s = 32; s >= 1; s >>= 1) m = fmaxf(m, __shfl_xor(m, s));
    if (lane == 0) att[wid] = m;
}

// ---------- dense 128x128 layer ----------
__global__ void k_dense128(const float* __restrict__ in, const float* __restrict__ w,
                           const float* __restrict__ bias, float* __restrict__ out,
                           int act /*0=relu,1=sigmoid*/) {
    int idx = blockIdx.x * blockDim.x + threadIdx.x;  // b*128 + j
    if (idx >= BB * 128) return;
    int j = idx % 128;
    int b = idx / 128;
    const float* ir = in + b * 128;
    const float* wr = w + j * 128;
    float acc = bias[j];
    for (int k = 0; k < 128; ++k) acc += ir[k] * wr[k];
    out[idx] = act ? (1.0f / (1.0f + expf(-acc))) : fmaxf(acc, 0.0f);
}

// ---------- d *= att[b,c] ----------
__global__ void k_scale(float* __restrict__ d, const float* __restrict__ att) {
    int idx = blockIdx.x * blockDim.x + threadIdx.x;
    int total = BB * 128 * NN;
    if (idx >= total) return;
    int c = (idx / NN) % 128;
    int b = idx / (NN * 128);
    d[idx] *= att[b * 128 + c];
}

// ---------- MLP layer 1: (B,2500)->(B,512), relu. one wave per output ----------
__global__ void k_mlp1(const float* __restrict__ flat, const float* __restrict__ w,
                       const float* __restrict__ bias, float* __restrict__ out) {
    int wid = blockIdx.x;   // b*512 + o
    int lane = threadIdx.x;
    int o = wid % 512;
    int b = wid / 512;
    const float* fr = flat + b * NN;
    const float* wr = w + (size_t)o * NN;
    float acc = 0.f;
    for (int n = lane; n < NN; n += 64) acc += fr[n] * wr[n];
    for (int s = 32; s >= 1; s >>= 1) acc += __shfl_xor(acc, s);
    if (lane == 0) out[wid] = fmaxf(acc + bias[o], 0.0f);
}

// ---------- MLP layer 2: (B,512)->(B,5), sigmoid ----------
__global__ void k_mlp2(const float* __restrict__ m, const float* __restrict__ w,
                       const float* __restrict__ bias, float* __restrict__ out) {
    int wid = blockIdx.x;   // b*5 + o
    int lane = threadIdx.x;
    int o = wid % 5;
    int b = wid / 5;
    const float* mr = m + b * 512;
    const float* wr = w + o * 512;
    float acc = 0.f;
    for (int k = lane; k < 512; k += 64) acc += mr[k] * wr[k];
    for (int s = 32; s >= 1; s >>= 1) acc += __shfl_xor(acc, s);
    if (lane == 0) out[wid] = 1.0f / (1.0f + expf(-(acc + bias[o])));
}

extern "C" void kernel_launch(void* const* d_in, const int* in_sizes, int n_in,
                              void* d_out, int out_size, void* d_ws, size_t ws_size,
                              hipStream_t stream) {
    const float* x       = (const float*)d_in[0];
    const float* Slist   = (const float*)d_in[1];
    const float* enc_w1  = (const float*)d_in[2];
    const float* enc_b1  = (const float*)d_in[3];
    const float* enc_w2  = (const float*)d_in[4];
    const float* enc_b2  = (const float*)d_in[5];
    const float* d0_a = (const float*)d_in[6];  const float* d0_W = (const float*)d_in[7];  const float* d0_b = (const float*)d_in[8];
    const float* d1_a = (const float*)d_in[9];  const float* d1_W = (const float*)d_in[10]; const float* d1_b = (const float*)d_in[11];
    const float* u0_a = (const float*)d_in[12]; const float* u0_W = (const float*)d_in[13]; const float* u0_b = (const float*)d_in[14];
    const float* u1_a = (const float*)d_in[15]; const float* u1_W = (const float*)d_in[16]; const float* u1_b = (const float*)d_in[17];
    const float* s0_a = (const float*)d_in[18]; const float* s0_W = (const float*)d_in[19]; const float* s0_b = (const float*)d_in[20];
    const float* s1_a = (const float*)d_in[21]; const float* s1_W = (const float*)d_in[22]; const float* s1_b = (const float*)d_in[23];
    const float* ca_w1 = (const float*)d_in[24]; const float* ca_b1 = (const float*)d_in[25];
    const float* ca_w2 = (const float*)d_in[26]; const float* ca_b2 = (const float*)d_in[27];
    const float* dec_w1 = (const float*)d_in[28]; const float* dec_b1 = (const float*)d_in[29];
    const float* dec_w2 = (const float*)d_in[30]; const float* dec_b2 = (const float*)d_in[31];
    const float* mlp_w1 = (const float*)d_in[32]; const float* mlp_b1 = (const float*)d_in[33];
    const float* mlp_w2 = (const float*)d_in[34]; const float* mlp_b2 = (const float*)d_in[35];
    float* out = (float*)d_out;

    // ---- workspace layout (f32 elements) ----
    float* ws = (float*)d_ws;
    size_t off = 0;
    auto alloc = [&](size_t n) { float* p = ws + off; off += n; return p; };
    float* sx    = alloc((size_t)BB * 3 * NN);
    float* h1    = alloc((size_t)BB * 32 * NN);
    float* f0    = alloc((size_t)BB * 32 * NN);
    float* xT_f0 = alloc((size_t)BB * NN * 32);
    float* f1    = alloc((size_t)BB * 64 * NN);
    float* xT_f1 = alloc((size_t)BB * NN * 64);
    float* f2    = alloc((size_t)BB * 32 * NN);
    float* xT_f2 = alloc((size_t)BB * NN * 32);
    float* g1    = alloc((size_t)BB * 64 * NN);
    float* xT_g1 = alloc((size_t)BB * NN * 64);
    float* g2    = alloc((size_t)BB * 128 * NN);
    float* s1b   = alloc((size_t)BB * PP * NN);
    float* s2b   = alloc((size_t)BB * PP * NN);
    int*   counts = (int*)alloc(2 * BB * NN);
    int*   cols   = (int*)alloc((size_t)2 * BB * NN * CAP);
    float* vals   = alloc((size_t)2 * BB * NN * CAP);
    float* att   = alloc(BB * 128);
    float* cah   = alloc(BB * 128);
    float* dec1o = alloc((size_t)BB * 32 * NN);
    float* dec2o = alloc((size_t)BB * NN);
    float* mbuf  = alloc((size_t)BB * 512);
    (void)ws_size;

    const int T = 256;

    // 1. sigmoid(x)
    k_sigmoid<<<cdiv(BB * 3 * NN, T), T, 0, stream>>>(x, sx, BB * 3 * NN);
    // 2-3. encoder convs
    k_conv3x3_relu<<<cdiv(BB * 32 * NN, T), T, 0, stream>>>(sx, enc_w1, enc_b1, h1, 3, 32, 0.0f);
    k_conv3x3_relu<<<cdiv(BB * 32 * NN, T), T, 0, stream>>>(h1, enc_w2, enc_b2, f0, 32, 32, 0.0f);
    // 4. adjacency for S0 (s=0) and S1 (s=1)
    k_build_adj<<<cdiv(2 * BB * NN * 64, T), T, 0, stream>>>(Slist, counts, cols, vals);
    const int* cnt0 = counts;             const int* cnt1 = counts + BB * NN;
    const int* col0 = cols;               const int* col1 = cols + (size_t)BB * NN * CAP;
    const float* val0 = vals;             const float* val1 = vals + (size_t)BB * NN * CAP;

    // 5. f1 = gat(f0, S0, down0)  G=32 F=16 -> PF=64
    k_transpose<<<cdiv(BB * NN * 32, T), T, 0, stream>>>(f0, xT_f0, 32);
    k_gat_s1s2<<<cdiv(BB * PP * NN, T), T, 0, stream>>>(xT_f0, d0_a, 32, s1b, s2b);
    k_gat_main<<<BB * PP * NN, 64, 0, stream>>>(xT_f0, 32, s1b, s2b, cnt0, col0, val0,
                                                d0_W, d0_b, 16, f1, 64, 0);
    // 6. f2 = gat(f1, S1, down1)  G=64 F=8 -> PF=32
    k_transpose<<<cdiv(BB * NN * 64, T), T, 0, stream>>>(f1, xT_f1, 64);
    k_gat_s1s2<<<cdiv(BB * PP * NN, T), T, 0, stream>>>(xT_f1, d1_a, 64, s1b, s2b);
    k_gat_main<<<BB * PP * NN, 64, 0, stream>>>(xT_f1, 64, s1b, s2b, cnt1, col1, val1,
                                                d1_W, d1_b, 8, f2, 32, 0);
    // 7. g1 = gat(f2, S1, up0) + gat(f1, S1, sc1)   G=32/64, F=16 -> PF=64
    k_transpose<<<cdiv(BB * NN * 32, T), T, 0, stream>>>(f2, xT_f2, 32);
    k_gat_s1s2<<<cdiv(BB * PP * NN, T), T, 0, stream>>>(xT_f2, u0_a, 32, s1b, s2b);
    k_gat_main<<<BB * PP * NN, 64, 0, stream>>>(xT_f2, 32, s1b, s2b, cnt1, col1, val1,
                                                u0_W, u0_b, 16, g1, 64, 0);
    k_gat_s1s2<<<cdiv(BB * PP * NN, T), T, 0, stream>>>(xT_f1, s1_a, 64, s1b, s2b);
    k_gat_main<<<BB * PP * NN, 64, 0, stream>>>(xT_f1, 64, s1b, s2b, cnt1, col1, val1,
                                                s1_W, s1_b, 16, g1, 64, 1);
    // 8. g2 = gat(g1, S0, up1) + gat(f0, S0, sc0)   F=32 -> PF=128
    k_transpose<<<cdiv(BB * NN * 64, T), T, 0, stream>>>(g1, xT_g1, 64);
    k_gat_s1s2<<<cdiv(BB * PP * NN, T), T, 0, stream>>>(xT_g1, u1_a, 64, s1b, s2b);
    k_gat_main<<<BB * PP * NN, 64, 0, stream>>>(xT_g1, 64, s1b, s2b, cnt0, col0, val0,
                                                u1_W, u1_b, 32, g2, 128, 0);
    k_gat_s1s2<<<cdiv(BB * PP * NN, T), T, 0, stream>>>(xT_f0, s0_a, 32, s1b, s2b);
    k_gat_main<<<BB * PP * NN, 64, 0, stream>>>(xT_f0, 32, s1b, s2b, cnt0, col0, val0,
                                                s0_W, s0_b, 32, g2, 128, 1);
    // 9. channel attention
    k_attmax<<<BB * 128, 64, 0, stream>>>(g2, att);
    k_dense128<<<cdiv(BB * 128, T), T, 0, stream>>>(att, ca_w1, ca_b1, cah, 0);
    k_dense128<<<cdiv(BB * 128, T), T, 0, stream>>>(cah, ca_w2, ca_b2, att, 1);
    k_scale<<<cdiv(BB * 128 * NN, T), T, 0, stream>>>(g2, att);
    // 10. decoder convs (pad -999)
    k_conv3x3_relu<<<cdiv(BB * 32 * NN, T), T, 0, stream>>>(g2, dec_w1, dec_b1, dec1o, 128, 32, -999.0f);
    k_conv3x3_relu<<<cdiv(BB * 1 * NN, T), T, 0, stream>>>(dec1o, dec_w2, dec_b2, dec2o, 32, 1, -999.0f);
    // 11. MLP head
    k_mlp1<<<BB * 512, 64, 0, stream>>>(dec2o, mlp_w1, mlp_b1, mbuf);
    k_mlp2<<<BB * 5, 64, 0, stream>>>(mbuf, mlp_w2, mlp_b2, out);
}

// Round 2
// 398.281 us; speedup vs baseline: 1.1746x; 1.1746x over previous
//
#include <hip/hip_runtime.h>
#include <hip/hip_bf16.h>
#include <math.h>

// ---- problem constants ----
#define BB 2
#define HH 50
#define WW 50
#define NN 2500            // H*W
#define PP 4
#define CAP 128            // max neighbors per row (density ~1% of 2500 ~ 25)
#define LRELU_SLOPE 0.2f
#define ZTOL 1e-9f
#define PXB 40             // ceil(2500/64)

static inline int cdiv(int a, int b) { return (a + b - 1) / b; }

// ---------- elementwise ----------
__global__ void k_sigmoid(const float* in, float* out, int n) {
    int i = blockIdx.x * blockDim.x + threadIdx.x;
    if (i < n) out[i] = 1.0f / (1.0f + expf(-in[i]));
}

// ---------- weight repack: w[oc][ic][tap] -> wre[(ic*9+tap)*OC + oc] ----------
__global__ void k_repack(const float* __restrict__ e1, const float* __restrict__ e2,
                         const float* __restrict__ dd1, const float* __restrict__ dd2,
                         float* __restrict__ r1, float* __restrict__ r2,
                         float* __restrict__ r3, float* __restrict__ r4) {
    int i = blockIdx.x * blockDim.x + threadIdx.x;
    if (i < 32 * 3 * 9)  { int oc = i / 27;  int rem = i % 27;  int ic = rem / 9; int tp = rem % 9; r1[(ic * 9 + tp) * 32 + oc] = e1[i]; }
    if (i < 32 * 32 * 9) { int oc = i / 288; int rem = i % 288; int ic = rem / 9; int tp = rem % 9; r2[(ic * 9 + tp) * 32 + oc] = e2[i]; }
    if (i < 32 * 128 * 9){ int oc = i / 1152;int rem = i % 1152;int ic = rem / 9; int tp = rem % 9; r3[(ic * 9 + tp) * 32 + oc] = dd1[i]; }
    if (i < 1 * 32 * 9)  { int oc = 0;       int rem = i;       int ic = rem / 9; int tp = rem % 9; r4[(ic * 9 + tp) * 1  + oc] = dd2[i]; }
}

// ---------- chunked conv3x3: partial sums over ic-chunks ----------
// wave = 64 consecutive pixels; thread accumulates all OC outputs in registers.
// wre layout: [(ic*9+tap)*OC + oc]  (wave-uniform contiguous loads)
template<int OC>
__launch_bounds__(64)
__global__ void k_conv3x3_part(const float* __restrict__ in, const float* __restrict__ wre,
                               float* __restrict__ part, int Cin, int nchunks, int icchunk,
                               float padval) {
    int bx = blockIdx.x;
    int pxb = bx % PXB;
    int chunk = (bx / PXB) % nchunks;
    int b = bx / (PXB * nchunks);
    int px = pxb * 64 + threadIdx.x;
    bool valid = px < NN;
    int x = px % WW, y = px / WW;

    float acc[OC];
#pragma unroll
    for (int oc = 0; oc < OC; ++oc) acc[oc] = 0.f;

    int ic0 = chunk * icchunk;
    int ic1 = ic0 + icchunk; if (ic1 > Cin) ic1 = Cin;

    for (int ic = ic0; ic < ic1; ++ic) {
        const float* ip = in + ((size_t)(b * Cin + ic)) * NN;
        float v[9];
#pragma unroll
        for (int ky = 0; ky < 3; ++ky) {
            int yy = y + ky - 1;
#pragma unroll
            for (int kx = 0; kx < 3; ++kx) {
                int xx = x + kx - 1;
                bool ok = valid && yy >= 0 && yy < HH && xx >= 0 && xx < WW;
                v[ky * 3 + kx] = ok ? ip[yy * WW + xx] : padval;
            }
        }
        const float* wp = wre + (size_t)ic * 9 * OC;
#pragma unroll
        for (int tp = 0; tp < 9; ++tp) {
            float vv = v[tp];
#pragma unroll
            for (int oc = 0; oc < OC; ++oc) acc[oc] += wp[tp * OC + oc] * vv;
        }
    }
    if (valid) {
#pragma unroll
        for (int oc = 0; oc < OC; ++oc)
            part[(((size_t)chunk * BB + b) * OC + oc) * NN + px] = acc[oc];
    }
}

// ---------- reduce chunks + bias + relu; optional dual-layout write ----------
__global__ void k_conv_reduce(const float* __restrict__ part, const float* __restrict__ bias,
                              float* __restrict__ out, float* __restrict__ xTout,
                              int OCr, int nchunks) {
    int idx = blockIdx.x * blockDim.x + threadIdx.x;
    int total = BB * OCr * NN;
    if (idx >= total) return;
    int px = idx % NN;
    int oc = (idx / NN) % OCr;
    int b = idx / (NN * OCr);
    float s = bias[oc];
    for (int c = 0; c < nchunks; ++c)
        s += part[(((size_t)c * BB + b) * OCr + oc) * NN + px];
    s = fmaxf(s, 0.f);
    if (out)   out[((size_t)(b * OCr + oc)) * NN + px] = s;
    if (xTout) xTout[((size_t)b * NN + px) * OCr + oc] = s;
}

// ---------- build sparse adjacency from Slist (B,2,N,N) ----------
__global__ void k_build_adj(const float* __restrict__ S, int* __restrict__ counts,
                            int* __restrict__ cols, float* __restrict__ vals) {
    int gid = blockIdx.x * blockDim.x + threadIdx.x;
    int wid = gid >> 6;
    int lane = threadIdx.x & 63;
    int nrows = 2 * BB * NN;
    if (wid >= nrows) return;
    int i = wid % NN;
    int b = (wid / NN) % BB;
    int s = wid / (NN * BB);
    const float* Srow = S + (((size_t)(b * 2 + s)) * NN + i) * NN;
    size_t rowbase = (size_t)wid * CAP;
    int cnt = 0;
    for (int base = 0; base < NN; base += 64) {
        int j = base + lane;
        bool act = (j < NN) && (fabsf(Srow[j]) > ZTOL);
        unsigned long long m = __ballot(act);
        int off = __popcll(m & ((1ull << lane) - 1ull));
        if (act && (cnt + off) < CAP) {
            cols[rowbase + cnt + off] = j;
            vals[rowbase + cnt + off] = Srow[j];
        }
        cnt += __popcll(m);
    }
    if (lane == 0) counts[wid] = (cnt < CAP) ? cnt : CAP;
}

// ---------- transpose (B,G,N) -> (B,N,G) (only used for... nothing now; kept unused) ----------

// ---------- GAT: s1[b,p,n], s2[b,p,n] ----------
__global__ void k_gat_s1s2(const float* __restrict__ xT, const float* __restrict__ a, int G,
                           float* __restrict__ s1, float* __restrict__ s2) {
    int idx = blockIdx.x * blockDim.x + threadIdx.x;
    int total = BB * PP * NN;
    if (idx >= total) return;
    int n = idx % NN;
    int p = (idx / NN) % PP;
    int b = idx / (NN * PP);
    const float* ar = a + p * 2 * G;
    const float* xr = xT + ((size_t)b * NN + n) * G;
    float a1 = 0.f, a2 = 0.f;
    for (int g = 0; g < G; ++g) {
        float v = xr[g];
        a1 += ar[g] * v;
        a2 += ar[G + g] * v;
    }
    s1[idx] = a1;
    s2[idx] = a2;
}

// ---------- GAT main v2: one 256-thread block (4 waves = 4 heads) per (b,i) ----------
// layout: 0 -> write transposed xTout[b][i][p*F+f] ; 1 -> write cmaj out[b][p*F+f][i]
__launch_bounds__(256)
__global__ void k_gat_main2(const float* __restrict__ xT, int G,
                            const float* __restrict__ s1, const float* __restrict__ s2,
                            const int* __restrict__ counts, const int* __restrict__ cols,
                            const float* __restrict__ vals,
                            const float* __restrict__ Wf, const float* __restrict__ bias, int F,
                            float* __restrict__ dst, int layout, int accumulate) {
    __shared__ int   csh[CAP];
    __shared__ float wsh[PP][CAP];
    __shared__ float xish[64];
    __shared__ float z1part[8][PP][64];
    __shared__ float z1sh[PP][64];

    int i = blockIdx.x % NN;
    int b = blockIdx.x / NN;
    int w = threadIdx.x >> 6;        // wave index == head p
    int lane = threadIdx.x & 63;

    int cnt = counts[b * NN + i];
    size_t rowbase = ((size_t)(b * NN + i)) * CAP;

    if (threadIdx.x < G)
        xish[threadIdx.x] = xT[((size_t)b * NN + i) * G + threadIdx.x];

    // ---- phase 1: per-head masked softmax * S ----
    float s1i = s1[(b * PP + w) * NN + i];
    float lmax = -1e30f;
    for (int jj = lane; jj < cnt; jj += 64) {
        int j = cols[rowbase + jj];
        if (w == 0) csh[jj] = j;
        float e = s1i + s2[(b * PP + w) * NN + j];
        e = (e < 0.f) ? LRELU_SLOPE * e : e;
        wsh[w][jj] = e;
        lmax = fmaxf(lmax, e);
    }
    for (int m = 32; m >= 1; m >>= 1) lmax = fmaxf(lmax, __shfl_xor(lmax, m));
    float lsum = 0.f;
    for (int jj = lane; jj < cnt; jj += 64) {
        float ex = expf(wsh[w][jj] - lmax);
        wsh[w][jj] = ex;
        lsum += ex;
    }
    for (int m = 32; m >= 1; m >>= 1) lsum += __shfl_xor(lsum, m);
    float inv = (cnt > 0) ? 1.0f / lsum : 0.f;
    for (int jj = lane; jj < cnt; jj += 64)
        wsh[w][jj] *= inv * vals[rowbase + jj];
    __syncthreads();

    // ---- phase 2: z1[p][g] = sum_j w[p][j] * xT[col_j][g], jj split across slices ----
    int nsl = 256 / G;               // 4 (G=64) or 8 (G=32)
    int g = threadIdx.x % G;
    int sl = threadIdx.x / G;
    float pa0 = 0.f, pa1 = 0.f, pa2 = 0.f, pa3 = 0.f;
    for (int jj = sl; jj < cnt; jj += nsl) {
        float xv = xT[((size_t)b * NN + csh[jj]) * G + g];
        pa0 += wsh[0][jj] * xv;
        pa1 += wsh[1][jj] * xv;
        pa2 += wsh[2][jj] * xv;
        pa3 += wsh[3][jj] * xv;
    }
    z1part[sl][0][g] = pa0;
    z1part[sl][1][g] = pa1;
    z1part[sl][2][g] = pa2;
    z1part[sl][3][g] = pa3;
    __syncthreads();
    if (threadIdx.x < PP * G) {
        int p = threadIdx.x / G;
        int gg = threadIdx.x % G;
        float s = 0.f;
        for (int s2i = 0; s2i < nsl; ++s2i) s += z1part[s2i][p][gg];
        z1sh[p][gg] = s;
    }
    __syncthreads();

    // ---- phase 3: y[p][f] = sum_g xi[g]*W0[g,f] + z1[p][g]*W1[g,f] + bias[f] ----
    int p = w;
    const float* W0 = Wf + ((size_t)(p * 2 + 0)) * G * F;
    const float* W1 = W0 + (size_t)G * F;
    for (int f = lane; f < F; f += 64) {
        float yv = bias[f];
        for (int gg = 0; gg < G; ++gg)
            yv += xish[gg] * W0[gg * F + f] + z1sh[p][gg] * W1[gg * F + f];
        int oc = p * F + f;
        float* d;
        if (layout == 0) d = dst + ((size_t)b * NN + i) * (PP * F) + oc;
        else             d = dst + ((size_t)(b * PP * F + oc)) * NN + i;
        if (accumulate) *d += yv; else *d = yv;
    }
}

// ---------- att = max over spatial ----------
__global__ void k_attmax(const float* __restrict__ d, float* __restrict__ att) {
    int wid = blockIdx.x;
    int lane = threadIdx.x;
    const float* row = d + (size_t)wid * NN;
    float m = -1e30f;
    for (int n = lane; n < NN; n += 64) m = fmaxf(m, row[n]);
    for (int s = 32; s >= 1; s >>= 1) m = fmaxf(m, __shfl_xor(m, s));
    if (lane == 0) att[wid] = m;
}

// ---------- dense 128x128 ----------
__global__ void k_dense128(const float* __restrict__ in, const float* __restrict__ w,
                           const float* __restrict__ bias, float* __restrict__ out, int act) {
    int idx = blockIdx.x * blockDim.x + threadIdx.x;
    if (idx >= BB * 128) return;
    int j = idx % 128;
    int b = idx / 128;
    const float* ir = in + b * 128;
    const float* wr = w + j * 128;
    float acc = bias[j];
    for (int k = 0; k < 128; ++k) acc += ir[k] * wr[k];
    out[idx] = act ? (1.0f / (1.0f + expf(-acc))) : fmaxf(acc, 0.0f);
}

// ---------- d *= att ----------
__global__ void k_scale(float* __restrict__ d, const float* __restrict__ att) {
    int idx = blockIdx.x * blockDim.x + threadIdx.x;
    int total = BB * 128 * NN;
    if (idx >= total) return;
    int c = (idx / NN) % 128;
    int b = idx / (NN * 128);
    d[idx] *= att[b * 128 + c];
}

// ---------- MLP ----------
__global__ void k_mlp1(const float* __restrict__ flat, const float* __restrict__ w,
                       const float* __restrict__ bias, float* __restrict__ out) {
    int wid = blockIdx.x;
    int lane = threadIdx.x;
    int o = wid % 512;
    int b = wid / 512;
    const float* fr = flat + b * NN;
    const float* wr = w + (size_t)o * NN;
    float acc = 0.f;
    for (int n = lane; n < NN; n += 64) acc += fr[n] * wr[n];
    for (int s = 32; s >= 1; s >>= 1) acc += __shfl_xor(acc, s);
    if (lane == 0) out[wid] = fmaxf(acc + bias[o], 0.0f);
}

__global__ void k_mlp2(const float* __restrict__ m, const float* __restrict__ w,
                       const float* __restrict__ bias, float* __restrict__ out) {
    int wid = blockIdx.x;
    int lane = threadIdx.x;
    int o = wid % 5;
    int b = wid / 5;
    const float* mr = m + b * 512;
    const float* wr = w + o * 512;
    float acc = 0.f;
    for (int k = lane; k < 512; k += 64) acc += mr[k] * wr[k];
    for (int s = 32; s >= 1; s >>= 1) acc += __shfl_xor(acc, s);
    if (lane == 0) out[wid] = 1.0f / (1.0f + expf(-(acc + bias[o])));
}

extern "C" void kernel_launch(void* const* d_in, const int* in_sizes, int n_in,
                              void* d_out, int out_size, void* d_ws, size_t ws_size,
                              hipStream_t stream) {
    const float* x       = (const float*)d_in[0];
    const float* Slist   = (const float*)d_in[1];
    const float* enc_w1  = (const float*)d_in[2];
    const float* enc_b1  = (const float*)d_in[3];
    const float* enc_w2  = (const float*)d_in[4];
    const float* enc_b2  = (const float*)d_in[5];
    const float* d0_a = (const float*)d_in[6];  const float* d0_W = (const float*)d_in[7];  const float* d0_b = (const float*)d_in[8];
    const float* d1_a = (const float*)d_in[9];  const float* d1_W = (const float*)d_in[10]; const float* d1_b = (const float*)d_in[11];
    const float* u0_a = (const float*)d_in[12]; const float* u0_W = (const float*)d_in[13]; const float* u0_b = (const float*)d_in[14];
    const float* u1_a = (const float*)d_in[15]; const float* u1_W = (const float*)d_in[16]; const float* u1_b = (const float*)d_in[17];
    const float* s0_a = (const float*)d_in[18]; const float* s0_W = (const float*)d_in[19]; const float* s0_b = (const float*)d_in[20];
    const float* s1_a = (const float*)d_in[21]; const float* s1_W = (const float*)d_in[22]; const float* s1_b = (const float*)d_in[23];
    const float* ca_w1 = (const float*)d_in[24]; const float* ca_b1 = (const float*)d_in[25];
    const float* ca_w2 = (const float*)d_in[26]; const float* ca_b2 = (const float*)d_in[27];
    const float* dec_w1 = (const float*)d_in[28]; const float* dec_b1 = (const float*)d_in[29];
    const float* dec_w2 = (const float*)d_in[30]; const float* dec_b2 = (const float*)d_in[31];
    const float* mlp_w1 = (const float*)d_in[32]; const float* mlp_b1 = (const float*)d_in[33];
    const float* mlp_w2 = (const float*)d_in[34]; const float* mlp_b2 = (const float*)d_in[35];
    float* out = (float*)d_out;

    // ---- workspace layout (f32 elements) ----
    float* ws = (float*)d_ws;
    size_t off = 0;
    auto alloc = [&](size_t n) { float* p = ws + off; off += n; return p; };
    float* sx    = alloc((size_t)BB * 3 * NN);
    float* h1    = alloc((size_t)BB * 32 * NN);
    float* xT_f0 = alloc((size_t)BB * NN * 32);
    float* xT_f1 = alloc((size_t)BB * NN * 64);
    float* xT_f2 = alloc((size_t)BB * NN * 32);
    float* xT_g1 = alloc((size_t)BB * NN * 64);
    float* g2    = alloc((size_t)BB * 128 * NN);
    float* s1b   = alloc((size_t)BB * PP * NN);
    float* s2b   = alloc((size_t)BB * PP * NN);
    int*   counts = (int*)alloc(2 * BB * NN);
    int*   cols   = (int*)alloc((size_t)2 * BB * NN * CAP);
    float* vals   = alloc((size_t)2 * BB * NN * CAP);
    float* att   = alloc(BB * 128);
    float* cah   = alloc(BB * 128);
    float* dec1o = alloc((size_t)BB * 32 * NN);
    float* dec2o = alloc((size_t)BB * NN);
    float* mbuf  = alloc((size_t)BB * 512);
    float* wre1  = alloc(32 * 3 * 9);
    float* wre2  = alloc(32 * 32 * 9);
    float* wre3  = alloc(32 * 128 * 9);
    float* wre4  = alloc(1 * 32 * 9);
    float* partial = alloc((size_t)8 * BB * 32 * NN);   // max: dec1 (8 chunks)
    (void)ws_size;

    const int T = 256;

    // 0. weight repack
    k_repack<<<cdiv(32 * 128 * 9, T), T, 0, stream>>>(enc_w1, enc_w2, dec_w1, dec_w2,
                                                      wre1, wre2, wre3, wre4);
    // 1. sigmoid(x)
    k_sigmoid<<<cdiv(BB * 3 * NN, T), T, 0, stream>>>(x, sx, BB * 3 * NN);
    // 2. enc conv1 (3->32), 1 chunk
    k_conv3x3_part<32><<<BB * 1 * PXB, 64, 0, stream>>>(sx, wre1, partial, 3, 1, 16, 0.0f);
    k_conv_reduce<<<cdiv(BB * 32 * NN, T), T, 0, stream>>>(partial, enc_b1, h1, nullptr, 32, 1);
    // 3. enc conv2 (32->32), 2 chunks -> f0 (only transposed layout needed)
    k_conv3x3_part<32><<<BB * 2 * PXB, 64, 0, stream>>>(h1, wre2, partial, 32, 2, 16, 0.0f);
    k_conv_reduce<<<cdiv(BB * 32 * NN, T), T, 0, stream>>>(partial, enc_b2, nullptr, xT_f0, 32, 2);
    // 4. adjacency
    k_build_adj<<<cdiv(2 * BB * NN * 64, T), T, 0, stream>>>(Slist, counts, cols, vals);
    const int* cnt0 = counts;             const int* cnt1 = counts + BB * NN;
    const int* col0 = cols;               const int* col1 = cols + (size_t)BB * NN * CAP;
    const float* val0 = vals;             const float* val1 = vals + (size_t)BB * NN * CAP;

    // 5. f1 = gat(f0, S0, down0)  G=32 F=16
    k_gat_s1s2<<<cdiv(BB * PP * NN, T), T, 0, stream>>>(xT_f0, d0_a, 32, s1b, s2b);
    k_gat_main2<<<BB * NN, 256, 0, stream>>>(xT_f0, 32, s1b, s2b, cnt0, col0, val0,
                                             d0_W, d0_b, 16, xT_f1, 0, 0);
    // 6. f2 = gat(f1, S1, down1)  G=64 F=8
    k_gat_s1s2<<<cdiv(BB * PP * NN, T), T, 0, stream>>>(xT_f1, d1_a, 64, s1b, s2b);
    k_gat_main2<<<BB * NN, 256, 0, stream>>>(xT_f1, 64, s1b, s2b, cnt1, col1, val1,
                                             d1_W, d1_b, 8, xT_f2, 0, 0);
    // 7. g1 = gat(f2, S1, up0) + gat(f1, S1, sc1)
    k_gat_s1s2<<<cdiv(BB * PP * NN, T), T, 0, stream>>>(xT_f2, u0_a, 32, s1b, s2b);
    k_gat_main2<<<BB * NN, 256, 0, stream>>>(xT_f2, 32, s1b, s2b, cnt1, col1, val1,
                                             u0_W, u0_b, 16, xT_g1, 0, 0);
    k_gat_s1s2<<<cdiv(BB * PP * NN, T), T, 0, stream>>>(xT_f1, s1_a, 64, s1b, s2b);
    k_gat_main2<<<BB * NN, 256, 0, stream>>>(xT_f1, 64, s1b, s2b, cnt1, col1, val1,
                                             s1_W, s1_b, 16, xT_g1, 0, 1);
    // 8. g2 = gat(g1, S0, up1) + gat(f0, S0, sc0)  (channel-major output)
    k_gat_s1s2<<<cdiv(BB * PP * NN, T), T, 0, stream>>>(xT_g1, u1_a, 64, s1b, s2b);
    k_gat_main2<<<BB * NN, 256, 0, stream>>>(xT_g1, 64, s1b, s2b, cnt0, col0, val0,
                                             u1_W, u1_b, 32, g2, 1, 0);
    k_gat_s1s2<<<cdiv(BB * PP * NN, T), T, 0, stream>>>(xT_f0, s0_a, 32, s1b, s2b);
    k_gat_main2<<<BB * NN, 256, 0, stream>>>(xT_f0, 32, s1b, s2b, cnt0, col0, val0,
                                             s0_W, s0_b, 32, g2, 1, 1);
    // 9. channel attention
    k_attmax<<<BB * 128, 64, 0, stream>>>(g2, att);
    k_dense128<<<cdiv(BB * 128, T), T, 0, stream>>>(att, ca_w1, ca_b1, cah, 0);
    k_dense128<<<cdiv(BB * 128, T), T, 0, stream>>>(cah, ca_w2, ca_b2, att, 1);
    k_scale<<<cdiv(BB * 128 * NN, T), T, 0, stream>>>(g2, att);
    // 10. decoder convs (pad -999)
    k_conv3x3_part<32><<<BB * 8 * PXB, 64, 0, stream>>>(g2, wre3, partial, 128, 8, 16, -999.0f);
    k_conv_reduce<<<cdiv(BB * 32 * NN, T), T, 0, stream>>>(partial, dec_b1, dec1o, nullptr, 32, 8);
    k_conv3x3_part<1><<<BB * 2 * PXB, 64, 0, stream>>>(dec1o, wre4, partial, 32, 2, 16, -999.0f);
    k_conv_reduce<<<cdiv(BB * 1 * NN, T), T, 0, stream>>>(partial, dec_b2, dec2o, nullptr, 1, 2);
    // 11. MLP head
    k_mlp1<<<BB * 512, 64, 0, stream>>>(dec2o, mlp_w1, mlp_b1, mbuf);
    k_mlp2<<<BB * 5, 64, 0, stream>>>(mbuf, mlp_w2, mlp_b2, out);
}

// Round 3
// 381.909 us; speedup vs baseline: 1.2250x; 1.0429x over previous
//
#include <hip/hip_runtime.h>
#include <hip/hip_bf16.h>
#include <math.h>

// ---- problem constants ----
#define BB 2
#define HH 50
#define WW 50
#define NN 2500            // H*W
#define PP 4
#define CAP 128            // max neighbors per row (density ~1% of 2500 ~ 25)
#define LRELU_SLOPE 0.2f
#define ZTOL 1e-9f
#define PXB 40             // ceil(2500/64)

static inline int cdiv(int a, int b) { return (a + b - 1) / b; }

// ---------- elementwise ----------
__global__ void k_sigmoid(const float* in, float* out, int n) {
    int i = blockIdx.x * blockDim.x + threadIdx.x;
    if (i < n) out[i] = 1.0f / (1.0f + expf(-in[i]));
}

// ---------- weight repack: w[oc][ic][tap] -> wre[(ic*9+tap)*OC + oc] ----------
__global__ void k_repack(const float* __restrict__ e1, const float* __restrict__ e2,
                         const float* __restrict__ dd1, const float* __restrict__ dd2,
                         float* __restrict__ r1, float* __restrict__ r2,
                         float* __restrict__ r3, float* __restrict__ r4) {
    int i = blockIdx.x * blockDim.x + threadIdx.x;
    if (i < 32 * 3 * 9)  { int oc = i / 27;  int rem = i % 27;  int ic = rem / 9; int tp = rem % 9; r1[(ic * 9 + tp) * 32 + oc] = e1[i]; }
    if (i < 32 * 32 * 9) { int oc = i / 288; int rem = i % 288; int ic = rem / 9; int tp = rem % 9; r2[(ic * 9 + tp) * 32 + oc] = e2[i]; }
    if (i < 32 * 128 * 9){ int oc = i / 1152;int rem = i % 1152;int ic = rem / 9; int tp = rem % 9; r3[(ic * 9 + tp) * 32 + oc] = dd1[i]; }
    if (i < 1 * 32 * 9)  { int oc = 0;       int rem = i;       int ic = rem / 9; int tp = rem % 9; r4[(ic * 9 + tp) * 1  + oc] = dd2[i]; }
}

// ---------- chunked conv3x3: partial sums over ic-chunks ----------
template<int OC>
__launch_bounds__(64)
__global__ void k_conv3x3_part(const float* __restrict__ in, const float* __restrict__ wre,
                               float* __restrict__ part, int Cin, int nchunks, int icchunk,
                               float padval) {
    int bx = blockIdx.x;
    int pxb = bx % PXB;
    int chunk = (bx / PXB) % nchunks;
    int b = bx / (PXB * nchunks);
    int px = pxb * 64 + threadIdx.x;
    bool valid = px < NN;
    int x = px % WW, y = px / WW;

    float acc[OC];
#pragma unroll
    for (int oc = 0; oc < OC; ++oc) acc[oc] = 0.f;

    int ic0 = chunk * icchunk;
    int ic1 = ic0 + icchunk; if (ic1 > Cin) ic1 = Cin;

    for (int ic = ic0; ic < ic1; ++ic) {
        const float* ip = in + ((size_t)(b * Cin + ic)) * NN;
        float v[9];
#pragma unroll
        for (int ky = 0; ky < 3; ++ky) {
            int yy = y + ky - 1;
#pragma unroll
            for (int kx = 0; kx < 3; ++kx) {
                int xx = x + kx - 1;
                bool ok = valid && yy >= 0 && yy < HH && xx >= 0 && xx < WW;
                v[ky * 3 + kx] = ok ? ip[yy * WW + xx] : padval;
            }
        }
        const float* wp = wre + (size_t)ic * 9 * OC;
#pragma unroll
        for (int tp = 0; tp < 9; ++tp) {
            float vv = v[tp];
#pragma unroll
            for (int oc = 0; oc < OC; ++oc) acc[oc] += wp[tp * OC + oc] * vv;
        }
    }
    if (valid) {
#pragma unroll
        for (int oc = 0; oc < OC; ++oc)
            part[(((size_t)chunk * BB + b) * OC + oc) * NN + px] = acc[oc];
    }
}

// ---------- reduce chunks + bias + relu; optional dual-layout write ----------
__global__ void k_conv_reduce(const float* __restrict__ part, const float* __restrict__ bias,
                              float* __restrict__ out, float* __restrict__ xTout,
                              int OCr, int nchunks) {
    int idx = blockIdx.x * blockDim.x + threadIdx.x;
    int total = BB * OCr * NN;
    if (idx >= total) return;
    int px = idx % NN;
    int oc = (idx / NN) % OCr;
    int b = idx / (NN * OCr);
    float s = bias[oc];
    for (int c = 0; c < nchunks; ++c)
        s += part[(((size_t)c * BB + b) * OCr + oc) * NN + px];
    s = fmaxf(s, 0.f);
    if (out)   out[((size_t)(b * OCr + oc)) * NN + px] = s;
    if (xTout) xTout[((size_t)b * NN + px) * OCr + oc] = s;
}

// ---------- build sparse adjacency from Slist (B,2,N,N) ----------
// v2: batch-load the whole row (10x float4/lane in flight), ballot-rank compaction.
// 2500 = 625 quads; row byte stride 10000 is 16B-aligned.
__launch_bounds__(256)
__global__ void k_build_adj(const float* __restrict__ S, int* __restrict__ counts,
                            int* __restrict__ cols, float* __restrict__ vals) {
    int wid = blockIdx.x * (blockDim.x >> 6) + (threadIdx.x >> 6);
    int lane = threadIdx.x & 63;
    int nrows = 2 * BB * NN;
    if (wid >= nrows) return;
    int i = wid % NN;
    int b = (wid / NN) % BB;
    int s = wid / (NN * BB);
    const float4* Srow = (const float4*)(S + (((size_t)(b * 2 + s)) * NN + i) * NN);
    size_t rowbase = (size_t)wid * CAP;
    unsigned long long below = (lane == 63) ? 0x7fffffffffffffffull
                                            : ((1ull << lane) - 1ull);

    // batch load: all 10 float4 issued before any dependent use
    float4 v[10];
#pragma unroll
    for (int it = 0; it < 10; ++it) {
        int q = it * 64 + lane;
        if (q < 625) v[it] = Srow[q];
        else         v[it] = make_float4(0.f, 0.f, 0.f, 0.f);
    }

    int cnt = 0;
#pragma unroll
    for (int it = 0; it < 10; ++it) {
        float4 f = v[it];
        float e0 = fabsf(f.x), e1 = fabsf(f.y), e2 = fabsf(f.z), e3 = fabsf(f.w);
        unsigned long long b0 = __ballot(e0 > ZTOL);
        unsigned long long b1 = __ballot(e1 > ZTOL);
        unsigned long long b2 = __ballot(e2 > ZTOL);
        unsigned long long b3 = __ballot(e3 > ZTOL);
        // rank of element (lane, j): all elements of lower lanes (any j) + same-lane j'<j
        int r0 = __popcll(b0 & below) + __popcll(b1 & below) +
                 __popcll(b2 & below) + __popcll(b3 & below);
        int basej = it * 256 + lane * 4;
        int idx = cnt + r0;
        bool a0 = (b0 >> lane) & 1, a1 = (b1 >> lane) & 1,
             a2 = (b2 >> lane) & 1, a3 = (b3 >> lane) & 1;
        if (a0) { if (idx < CAP) { cols[rowbase + idx] = basej + 0; vals[rowbase + idx] = f.x; } ++idx; }
        if (a1) { if (idx < CAP) { cols[rowbase + idx] = basej + 1; vals[rowbase + idx] = f.y; } ++idx; }
        if (a2) { if (idx < CAP) { cols[rowbase + idx] = basej + 2; vals[rowbase + idx] = f.z; } ++idx; }
        if (a3) { if (idx < CAP) { cols[rowbase + idx] = basej + 3; vals[rowbase + idx] = f.w; } ++idx; }
        cnt += __popcll(b0) + __popcll(b1) + __popcll(b2) + __popcll(b3);
    }
    if (lane == 0) counts[wid] = (cnt < CAP) ? cnt : CAP;
}

// ---------- GAT: s1[b,p,n], s2[b,p,n] ----------
__global__ void k_gat_s1s2(const float* __restrict__ xT, const float* __restrict__ a, int G,
                           float* __restrict__ s1, float* __restrict__ s2) {
    int idx = blockIdx.x * blockDim.x + threadIdx.x;
    int total = BB * PP * NN;
    if (idx >= total) return;
    int n = idx % NN;
    int p = (idx / NN) % PP;
    int b = idx / (NN * PP);
    const float* ar = a + p * 2 * G;
    const float* xr = xT + ((size_t)b * NN + n) * G;
    float a1 = 0.f, a2 = 0.f;
    for (int g = 0; g < G; ++g) {
        float v = xr[g];
        a1 += ar[g] * v;
        a2 += ar[G + g] * v;
    }
    s1[idx] = a1;
    s2[idx] = a2;
}

// ---------- GAT main v2: one 256-thread block (4 waves = 4 heads) per (b,i) ----------
__launch_bounds__(256)
__global__ void k_gat_main2(const float* __restrict__ xT, int G,
                            const float* __restrict__ s1, const float* __restrict__ s2,
                            const int* __restrict__ counts, const int* __restrict__ cols,
                            const float* __restrict__ vals,
                            const float* __restrict__ Wf, const float* __restrict__ bias, int F,
                            float* __restrict__ dst, int layout, int accumulate) {
    __shared__ int   csh[CAP];
    __shared__ float wsh[PP][CAP];
    __shared__ float xish[64];
    __shared__ float z1part[8][PP][64];
    __shared__ float z1sh[PP][64];

    int i = blockIdx.x % NN;
    int b = blockIdx.x / NN;
    int w = threadIdx.x >> 6;        // wave index == head p
    int lane = threadIdx.x & 63;

    int cnt = counts[b * NN + i];
    size_t rowbase = ((size_t)(b * NN + i)) * CAP;

    if (threadIdx.x < G)
        xish[threadIdx.x] = xT[((size_t)b * NN + i) * G + threadIdx.x];

    // ---- phase 1: per-head masked softmax * S ----
    float s1i = s1[(b * PP + w) * NN + i];
    float lmax = -1e30f;
    for (int jj = lane; jj < cnt; jj += 64) {
        int j = cols[rowbase + jj];
        if (w == 0) csh[jj] = j;
        float e = s1i + s2[(b * PP + w) * NN + j];
        e = (e < 0.f) ? LRELU_SLOPE * e : e;
        wsh[w][jj] = e;
        lmax = fmaxf(lmax, e);
    }
    for (int m = 32; m >= 1; m >>= 1) lmax = fmaxf(lmax, __shfl_xor(lmax, m));
    float lsum = 0.f;
    for (int jj = lane; jj < cnt; jj += 64) {
        float ex = expf(wsh[w][jj] - lmax);
        wsh[w][jj] = ex;
        lsum += ex;
    }
    for (int m = 32; m >= 1; m >>= 1) lsum += __shfl_xor(lsum, m);
    float inv = (cnt > 0) ? 1.0f / lsum : 0.f;
    for (int jj = lane; jj < cnt; jj += 64)
        wsh[w][jj] *= inv * vals[rowbase + jj];
    __syncthreads();

    // ---- phase 2: z1[p][g] = sum_j w[p][j] * xT[col_j][g] ----
    int nsl = 256 / G;               // 4 (G=64) or 8 (G=32)
    int g = threadIdx.x % G;
    int sl = threadIdx.x / G;
    float pa0 = 0.f, pa1 = 0.f, pa2 = 0.f, pa3 = 0.f;
    for (int jj = sl; jj < cnt; jj += nsl) {
        float xv = xT[((size_t)b * NN + csh[jj]) * G + g];
        pa0 += wsh[0][jj] * xv;
        pa1 += wsh[1][jj] * xv;
        pa2 += wsh[2][jj] * xv;
        pa3 += wsh[3][jj] * xv;
    }
    z1part[sl][0][g] = pa0;
    z1part[sl][1][g] = pa1;
    z1part[sl][2][g] = pa2;
    z1part[sl][3][g] = pa3;
    __syncthreads();
    if (threadIdx.x < PP * G) {
        int p = threadIdx.x / G;
        int gg = threadIdx.x % G;
        float s = 0.f;
        for (int s2i = 0; s2i < nsl; ++s2i) s += z1part[s2i][p][gg];
        z1sh[p][gg] = s;
    }
    __syncthreads();

    // ---- phase 3: y[p][f] ----
    int p = w;
    const float* W0 = Wf + ((size_t)(p * 2 + 0)) * G * F;
    const float* W1 = W0 + (size_t)G * F;
    for (int f = lane; f < F; f += 64) {
        float yv = bias[f];
        for (int gg = 0; gg < G; ++gg)
            yv += xish[gg] * W0[gg * F + f] + z1sh[p][gg] * W1[gg * F + f];
        int oc = p * F + f;
        float* d;
        if (layout == 0) d = dst + ((size_t)b * NN + i) * (PP * F) + oc;
        else             d = dst + ((size_t)(b * PP * F + oc)) * NN + i;
        if (accumulate) *d += yv; else *d = yv;
    }
}

// ---------- att = max over spatial ----------
__global__ void k_attmax(const float* __restrict__ d, float* __restrict__ att) {
    int wid = blockIdx.x;
    int lane = threadIdx.x;
    const float* row = d + (size_t)wid * NN;
    float m = -1e30f;
    for (int n = lane; n < NN; n += 64) m = fmaxf(m, row[n]);
    for (int s = 32; s >= 1; s >>= 1) m = fmaxf(m, __shfl_xor(m, s));
    if (lane == 0) att[wid] = m;
}

// ---------- dense 128x128 ----------
__global__ void k_dense128(const float* __restrict__ in, const float* __restrict__ w,
                           const float* __restrict__ bias, float* __restrict__ out, int act) {
    int idx = blockIdx.x * blockDim.x + threadIdx.x;
    if (idx >= BB * 128) return;
    int j = idx % 128;
    int b = idx / 128;
    const float* ir = in + b * 128;
    const float* wr = w + j * 128;
    float acc = bias[j];
    for (int k = 0; k < 128; ++k) acc += ir[k] * wr[k];
    out[idx] = act ? (1.0f / (1.0f + expf(-acc))) : fmaxf(acc, 0.0f);
}

// ---------- d *= att ----------
__global__ void k_scale(float* __restrict__ d, const float* __restrict__ att) {
    int idx = blockIdx.x * blockDim.x + threadIdx.x;
    int total = BB * 128 * NN;
    if (idx >= total) return;
    int c = (idx / NN) % 128;
    int b = idx / (NN * 128);
    d[idx] *= att[b * 128 + c];
}

// ---------- MLP ----------
__global__ void k_mlp1(const float* __restrict__ flat, const float* __restrict__ w,
                       const float* __restrict__ bias, float* __restrict__ out) {
    int wid = blockIdx.x;
    int lane = threadIdx.x;
    int o = wid % 512;
    int b = wid / 512;
    const float* fr = flat + b * NN;
    const float* wr = w + (size_t)o * NN;
    float acc = 0.f;
    for (int n = lane; n < NN; n += 64) acc += fr[n] * wr[n];
    for (int s = 32; s >= 1; s >>= 1) acc += __shfl_xor(acc, s);
    if (lane == 0) out[wid] = fmaxf(acc + bias[o], 0.0f);
}

__global__ void k_mlp2(const float* __restrict__ m, const float* __restrict__ w,
                       const float* __restrict__ bias, float* __restrict__ out) {
    int wid = blockIdx.x;
    int lane = threadIdx.x;
    int o = wid % 5;
    int b = wid / 5;
    const float* mr = m + b * 512;
    const float* wr = w + o * 512;
    float acc = 0.f;
    for (int k = lane; k < 512; k += 64) acc += mr[k] * wr[k];
    for (int s = 32; s >= 1; s >>= 1) acc += __shfl_xor(acc, s);
    if (lane == 0) out[wid] = 1.0f / (1.0f + expf(-(acc + bias[o])));
}

extern "C" void kernel_launch(void* const* d_in, const int* in_sizes, int n_in,
                              void* d_out, int out_size, void* d_ws, size_t ws_size,
                              hipStream_t stream) {
    const float* x       = (const float*)d_in[0];
    const float* Slist   = (const float*)d_in[1];
    const float* enc_w1  = (const float*)d_in[2];
    const float* enc_b1  = (const float*)d_in[3];
    const float* enc_w2  = (const float*)d_in[4];
    const float* enc_b2  = (const float*)d_in[5];
    const float* d0_a = (const float*)d_in[6];  const float* d0_W = (const float*)d_in[7];  const float* d0_b = (const float*)d_in[8];
    const float* d1_a = (const float*)d_in[9];  const float* d1_W = (const float*)d_in[10]; const float* d1_b = (const float*)d_in[11];
    const float* u0_a = (const float*)d_in[12]; const float* u0_W = (const float*)d_in[13]; const float* u0_b = (const float*)d_in[14];
    const float* u1_a = (const float*)d_in[15]; const float* u1_W = (const float*)d_in[16]; const float* u1_b = (const float*)d_in[17];
    const float* s0_a = (const float*)d_in[18]; const float* s0_W = (const float*)d_in[19]; const float* s0_b = (const float*)d_in[20];
    const float* s1_a = (const float*)d_in[21]; const float* s1_W = (const float*)d_in[22]; const float* s1_b = (const float*)d_in[23];
    const float* ca_w1 = (const float*)d_in[24]; const float* ca_b1 = (const float*)d_in[25];
    const float* ca_w2 = (const float*)d_in[26]; const float* ca_b2 = (const float*)d_in[27];
    const float* dec_w1 = (const float*)d_in[28]; const float* dec_b1 = (const float*)d_in[29];
    const float* dec_w2 = (const float*)d_in[30]; const float* dec_b2 = (const float*)d_in[31];
    const float* mlp_w1 = (const float*)d_in[32]; const float* mlp_b1 = (const float*)d_in[33];
    const float* mlp_w2 = (const float*)d_in[34]; const float* mlp_b2 = (const float*)d_in[35];
    float* out = (float*)d_out;

    // ---- workspace layout (f32 elements) ----
    float* ws = (float*)d_ws;
    size_t off = 0;
    auto alloc = [&](size_t n) { float* p = ws + off; off += n; return p; };
    float* sx    = alloc((size_t)BB * 3 * NN);
    float* h1    = alloc((size_t)BB * 32 * NN);
    float* xT_f0 = alloc((size_t)BB * NN * 32);
    float* xT_f1 = alloc((size_t)BB * NN * 64);
    float* xT_f2 = alloc((size_t)BB * NN * 32);
    float* xT_g1 = alloc((size_t)BB * NN * 64);
    float* g2    = alloc((size_t)BB * 128 * NN);
    float* s1b   = alloc((size_t)BB * PP * NN);
    float* s2b   = alloc((size_t)BB * PP * NN);
    int*   counts = (int*)alloc(2 * BB * NN);
    int*   cols   = (int*)alloc((size_t)2 * BB * NN * CAP);
    float* vals   = alloc((size_t)2 * BB * NN * CAP);
    float* att   = alloc(BB * 128);
    float* cah   = alloc(BB * 128);
    float* dec1o = alloc((size_t)BB * 32 * NN);
    float* dec2o = alloc((size_t)BB * NN);
    float* mbuf  = alloc((size_t)BB * 512);
    float* wre1  = alloc(32 * 3 * 9);
    float* wre2  = alloc(32 * 32 * 9);
    float* wre3  = alloc(32 * 128 * 9);
    float* wre4  = alloc(1 * 32 * 9);
    float* partial = alloc((size_t)8 * BB * 32 * NN);   // max: dec1 (8 chunks)
    (void)ws_size;

    const int T = 256;

    // 0. weight repack
    k_repack<<<cdiv(32 * 128 * 9, T), T, 0, stream>>>(enc_w1, enc_w2, dec_w1, dec_w2,
                                                      wre1, wre2, wre3, wre4);
    // 1. sigmoid(x)
    k_sigmoid<<<cdiv(BB * 3 * NN, T), T, 0, stream>>>(x, sx, BB * 3 * NN);
    // 2. enc conv1 (3->32), 1 chunk
    k_conv3x3_part<32><<<BB * 1 * PXB, 64, 0, stream>>>(sx, wre1, partial, 3, 1, 16, 0.0f);
    k_conv_reduce<<<cdiv(BB * 32 * NN, T), T, 0, stream>>>(partial, enc_b1, h1, nullptr, 32, 1);
    // 3. enc conv2 (32->32), 2 chunks -> f0 (transposed layout)
    k_conv3x3_part<32><<<BB * 2 * PXB, 64, 0, stream>>>(h1, wre2, partial, 32, 2, 16, 0.0f);
    k_conv_reduce<<<cdiv(BB * 32 * NN, T), T, 0, stream>>>(partial, enc_b2, nullptr, xT_f0, 32, 2);
    // 4. adjacency
    k_build_adj<<<cdiv(2 * BB * NN, 4), 256, 0, stream>>>(Slist, counts, cols, vals);
    const int* cnt0 = counts;             const int* cnt1 = counts + BB * NN;
    const int* col0 = cols;               const int* col1 = cols + (size_t)BB * NN * CAP;
    const float* val0 = vals;             const float* val1 = vals + (size_t)BB * NN * CAP;

    // 5. f1 = gat(f0, S0, down0)  G=32 F=16
    k_gat_s1s2<<<cdiv(BB * PP * NN, T), T, 0, stream>>>(xT_f0, d0_a, 32, s1b, s2b);
    k_gat_main2<<<BB * NN, 256, 0, stream>>>(xT_f0, 32, s1b, s2b, cnt0, col0, val0,
                                             d0_W, d0_b, 16, xT_f1, 0, 0);
    // 6. f2 = gat(f1, S1, down1)  G=64 F=8
    k_gat_s1s2<<<cdiv(BB * PP * NN, T), T, 0, stream>>>(xT_f1, d1_a, 64, s1b, s2b);
    k_gat_main2<<<BB * NN, 256, 0, stream>>>(xT_f1, 64, s1b, s2b, cnt1, col1, val1,
                                             d1_W, d1_b, 8, xT_f2, 0, 0);
    // 7. g1 = gat(f2, S1, up0) + gat(f1, S1, sc1)
    k_gat_s1s2<<<cdiv(BB * PP * NN, T), T, 0, stream>>>(xT_f2, u0_a, 32, s1b, s2b);
    k_gat_main2<<<BB * NN, 256, 0, stream>>>(xT_f2, 32, s1b, s2b, cnt1, col1, val1,
                                             u0_W, u0_b, 16, xT_g1, 0, 0);
    k_gat_s1s2<<<cdiv(BB * PP * NN, T), T, 0, stream>>>(xT_f1, s1_a, 64, s1b, s2b);
    k_gat_main2<<<BB * NN, 256, 0, stream>>>(xT_f1, 64, s1b, s2b, cnt1, col1, val1,
                                             s1_W, s1_b, 16, xT_g1, 0, 1);
    // 8. g2 = gat(g1, S0, up1) + gat(f0, S0, sc0)  (channel-major output)
    k_gat_s1s2<<<cdiv(BB * PP * NN, T), T, 0, stream>>>(xT_g1, u1_a, 64, s1b, s2b);
    k_gat_main2<<<BB * NN, 256, 0, stream>>>(xT_g1, 64, s1b, s2b, cnt0, col0, val0,
                                             u1_W, u1_b, 32, g2, 1, 0);
    k_gat_s1s2<<<cdiv(BB * PP * NN, T), T, 0, stream>>>(xT_f0, s0_a, 32, s1b, s2b);
    k_gat_main2<<<BB * NN, 256, 0, stream>>>(xT_f0, 32, s1b, s2b, cnt0, col0, val0,
                                             s0_W, s0_b, 32, g2, 1, 1);
    // 9. channel attention
    k_attmax<<<BB * 128, 64, 0, stream>>>(g2, att);
    k_dense128<<<cdiv(BB * 128, T), T, 0, stream>>>(att, ca_w1, ca_b1, cah, 0);
    k_dense128<<<cdiv(BB * 128, T), T, 0, stream>>>(cah, ca_w2, ca_b2, att, 1);
    k_scale<<<cdiv(BB * 128 * NN, T), T, 0, stream>>>(g2, att);
    // 10. decoder convs (pad -999)
    k_conv3x3_part<32><<<BB * 8 * PXB, 64, 0, stream>>>(g2, wre3, partial, 128, 8, 16, -999.0f);
    k_conv_reduce<<<cdiv(BB * 32 * NN, T), T, 0, stream>>>(partial, dec_b1, dec1o, nullptr, 32, 8);
    k_conv3x3_part<1><<<BB * 2 * PXB, 64, 0, stream>>>(dec1o, wre4, partial, 32, 2, 16, -999.0f);
    k_conv_reduce<<<cdiv(BB * 1 * NN, T), T, 0, stream>>>(partial, dec_b2, dec2o, nullptr, 1, 2);
    // 11. MLP head
    k_mlp1<<<BB * 512, 64, 0, stream>>>(dec2o, mlp_w1, mlp_b1, mbuf);
    k_mlp2<<<BB * 5, 64, 0, stream>>>(mbuf, mlp_w2, mlp_b2, out);
}